// Round 16
// baseline (99.879 us; speedup 1.0000x reference)
//
#include <hip/hip_runtime.h>
#include <hip/hip_bf16.h>
#include <math.h>

#define NB 16
#define RB 64
#define HB 128
#define WB 128
#define DB 256
#define HW (HB * WB)
#define LOG2E 1.4426950408889634f

typedef __attribute__((ext_vector_type(8))) short bf16x8;
typedef __attribute__((ext_vector_type(4))) short short4v;
typedef __attribute__((ext_vector_type(4))) float f32x4;

static __device__ __forceinline__ short f2bf(float f) {
  __hip_bfloat16 h = __float2bfloat16(f);
  return *reinterpret_cast<short*>(&h);
}
static __device__ __forceinline__ float bf2f(short s) {
  return __uint_as_float(((unsigned)(unsigned short)s) << 16);
}

// Analytic per-axis max of -(|g-mu|/sg)^2 over grid g_i=(i+0.5)/128:
// attained at the grid point nearest mu (R10-verified bitwise vs reduction).
static __device__ __forceinline__ float axis_maxlog(float mu, float sg) {
  int i = (int)roundf(mu * 128.0f - 0.5f);
  i = i < 0 ? 0 : (i > 127 ? 127 : i);
  const float g = (i + 0.5f) * (1.0f / 128.0f);
  const float tm = fabsf(g - mu) / sg;
  return -(tm * tm);
}

// feat v14: R15's no-LDS streaming kernel with DEPTH-3 prefetch.
// Step i consumes buffer i%3 and issues loads for step i+2 into (i+2)%3:
// each buffer ages ~2 compute-steps (>=600cy) before use; x2 waves/SIMD
// covers the ~900cy HBM latency. Buffers = 96 VGPR, total ~220 (fits 256).
template <bool WITHMAP>
__global__ __launch_bounds__(256, 2) void feat_kernel(
    const float* __restrict__ x, const float* __restrict__ roi,
    short* __restrict__ partials, float* __restrict__ out_map) {
  __shared__ float sT[1024];            // map path only (4 KB)

  const int bid = blockIdx.x;
  const int t   = threadIdx.x;

  if (WITHMAP && bid >= 512) {
    // ---------------- map path (R13-proven logic, 256 thr) ----------------
    const int mb = bid - 512;           // 0..255, 4 rois each
    float* sEx = sT;
    float* sEy = sT + 512;
    for (int v = t; v < 1024; v += 256) {
      const int rr = v >> 8, axis = (v >> 7) & 1, pos = v & 127;
      const float4 rp = reinterpret_cast<const float4*>(roi)[mb * 4 + rr];
      const float mlx = axis_maxlog(rp.x, rp.z);
      const float mly = axis_maxlog(rp.y, rp.w);
      const float em  = expf(mlx + mly);
      const float s   = em / (em + 1e-12f);
      const float g   = (pos + 0.5f) * (1.0f / 128.0f);
      if (axis == 0) {
        const float tx = fabsf(g - rp.x) / rp.z;
        sEx[rr * 128 + pos] = expf(-(tx * tx) - mlx);
      } else {
        const float ty = fabsf(g - rp.y) / rp.w;
        sEy[rr * 128 + pos] = expf(-(ty * ty) - mly) * s;
      }
    }
    __syncthreads();
    f32x4* dst = reinterpret_cast<f32x4*>(out_map + (size_t)mb * 4 * HW);
#pragma unroll 8
    for (int p = 0; p < 64; ++p) {
      const int idx = p * 256 + t;      // 16384 f32x4 per block
      const int rr = idx >> 12, h = (idx >> 5) & 127, w4 = idx & 31;
      const f32x4 e = *reinterpret_cast<const f32x4*>(&sEx[rr * 128 + w4 * 4]);
      dst[idx] = e * (f32x4)sEy[rr * 128 + h];
    }
    return;
  }

  // ---------------- feat path ----------------
  const int n   = bid >> 5;
  const int hc  = bid & 31;
  const int l   = t & 63;
  const int wv  = t >> 6;               // 0..3 -> d-slice
  const int l15 = l & 15;
  const int lk  = (l >> 4) * 8;         // lane's k-offset within a k-step
  const int h0  = hc * 4;               // first h-row of this chunk
  const int dbase = wv * 64 + l15 * 4;

  // f32x4-granular base: pixel p, this lane's d-quad = gx4[p*64 + wv*16 + l15]
  const f32x4* gx4 =
      reinterpret_cast<const f32x4*>(x + ((size_t)n * HW + (size_t)hc * 512) * DB);
  const int lquad = wv * 16 + l15;

  // ---- prologue: per-rf roi params (exp2-domain) + ey row values ----
  float mux[4], c2x[4], mlx2[4];        // c2x = log2e/sg^2, mlx2 = log2e*mlx
  float eyv[4][4];                      // [hh][rf]
#pragma unroll
  for (int rf = 0; rf < 4; ++rf) {
    const int nr = n * RB + rf * 16 + l15;
    const float4 rp = reinterpret_cast<const float4*>(roi)[nr];
    const float mlx_ = axis_maxlog(rp.x, rp.z);
    const float mly_ = axis_maxlog(rp.y, rp.w);
    const float em   = expf(mlx_ + mly_);
    const float s    = em / (em + 1e-12f);
    const float isx  = 1.0f / rp.z;
    mux[rf] = rp.x; c2x[rf] = isx * isx * LOG2E; mlx2[rf] = mlx_ * LOG2E;
#pragma unroll
    for (int hh = 0; hh < 4; ++hh) {
      const float g = (h0 + hh + 0.5f) * (1.0f / 128.0f);
      const float ty = fabsf(g - rp.y) / rp.w;
      eyv[hh][rf] = expf(-(ty * ty) - mly_) * s;
    }
  }

  f32x4 acc[4][4];
#pragma unroll
  for (int rf = 0; rf < 4; ++rf)
#pragma unroll
    for (int f = 0; f < 4; ++f) acc[rf][f] = (f32x4)0.0f;

  f32x4 xva[8], xvb[8], xvc[8];         // depth-3 named buffers (rule #20)

#define GLOAD(BUFN, bi) do {                                                 \
    _Pragma("unroll")                                                        \
    for (int j = 0; j < 8; ++j)                                              \
      BUFN[j] = gx4[(size_t)((bi) * 32 + lk + j) * 64 + lquad];              \
  } while (0)

#define KSTEP(bi, CUR, NXT) do {                                             \
    if ((bi) < 14) GLOAD(NXT, (bi) + 2);                                     \
    bf16x8 bfr_[4];                                                          \
    _Pragma("unroll")                                                        \
    for (int f = 0; f < 4; ++f) {                                            \
      bf16x8 b_;                                                             \
      _Pragma("unroll")                                                      \
      for (int j = 0; j < 8; ++j) b_[j] = f2bf(CUR[j][f]);                   \
      bfr_[f] = b_;                                                          \
    }                                                                        \
    bf16x8 afr_[4];                                                          \
    _Pragma("unroll")                                                        \
    for (int rf = 0; rf < 4; ++rf) {                                         \
      const float ey_ = eyv[(bi) >> 2][rf];                                  \
      bf16x8 a_;                                                             \
      _Pragma("unroll")                                                      \
      for (int i = 0; i < 8; ++i) {                                          \
        const int col = ((bi) & 3) * 32 + lk + i;                            \
        const float g_ = (col + 0.5f) * (1.0f / 128.0f);                     \
        const float d_ = g_ - mux[rf];                                       \
        const float e_ = exp2f(-(d_ * d_ * c2x[rf]) - mlx2[rf]);             \
        a_[i] = f2bf(ey_ * e_);                                              \
      }                                                                      \
      afr_[rf] = a_;                                                         \
    }                                                                        \
    _Pragma("unroll")                                                        \
    for (int rf = 0; rf < 4; ++rf)                                           \
      _Pragma("unroll")                                                      \
      for (int f = 0; f < 4; ++f)                                            \
        acc[rf][f] = __builtin_amdgcn_mfma_f32_16x16x32_bf16(                \
            afr_[rf], bfr_[f], acc[rf][f], 0, 0, 0);                         \
  } while (0)

  GLOAD(xva, 0);
  GLOAD(xvb, 1);
  KSTEP(0,  xva, xvc); KSTEP(1,  xvb, xva); KSTEP(2,  xvc, xvb);
  KSTEP(3,  xva, xvc); KSTEP(4,  xvb, xva); KSTEP(5,  xvc, xvb);
  KSTEP(6,  xva, xvc); KSTEP(7,  xvb, xva); KSTEP(8,  xvc, xvb);
  KSTEP(9,  xva, xvc); KSTEP(10, xvb, xva); KSTEP(11, xvc, xvb);
  KSTEP(12, xva, xvc); KSTEP(13, xvb, xva); KSTEP(14, xvc, xvb);
  KSTEP(15, xva, xvc);

#undef KSTEP
#undef GLOAD

  // ---- epilogue: bf16 partial tile, plain coalesced 8B stores ----
  // D layout: col = lane&15 (-> d, +f over vector), row = (lane>>4)*4 + reg.
  short* P = partials + (size_t)bid * (RB * DB);
#pragma unroll
  for (int rf = 0; rf < 4; ++rf) {
#pragma unroll
    for (int reg = 0; reg < 4; ++reg) {
      const int r = rf * 16 + (l >> 4) * 4 + reg;
      short4v v;
      v.x = f2bf(acc[rf][0][reg]); v.y = f2bf(acc[rf][1][reg]);
      v.z = f2bf(acc[rf][2][reg]); v.w = f2bf(acc[rf][3][reg]);
      *reinterpret_cast<short4v*>(P + (size_t)r * DB + dbase) = v;
    }
  }
}

// Analytic map writer (fallback path only; 256 thr).
__global__ __launch_bounds__(256) void map_only_kernel(
    const float* __restrict__ roi, float* __restrict__ out_map) {
  __shared__ float sT[1024];
  const int mb = blockIdx.x;            // 0..255, 4 rois each
  const int t  = threadIdx.x;
  float* sEx = sT;
  float* sEy = sT + 512;
  for (int v = t; v < 1024; v += 256) {
    const int rr = v >> 8, axis = (v >> 7) & 1, pos = v & 127;
    const float4 rp = reinterpret_cast<const float4*>(roi)[mb * 4 + rr];
    const float mlx = axis_maxlog(rp.x, rp.z);
    const float mly = axis_maxlog(rp.y, rp.w);
    const float em  = expf(mlx + mly);
    const float s   = em / (em + 1e-12f);
    const float g   = (pos + 0.5f) * (1.0f / 128.0f);
    if (axis == 0) {
      const float tx = fabsf(g - rp.x) / rp.z;
      sEx[rr * 128 + pos] = expf(-(tx * tx) - mlx);
    } else {
      const float ty = fabsf(g - rp.y) / rp.w;
      sEy[rr * 128 + pos] = expf(-(ty * ty) - mly) * s;
    }
  }
  __syncthreads();
  f32x4* dst = reinterpret_cast<f32x4*>(out_map + (size_t)mb * 4 * HW);
#pragma unroll 8
  for (int p = 0; p < 64; ++p) {
    const int idx = p * 256 + t;
    const int rr = idx >> 12, h = (idx >> 5) & 127, w4 = idx & 31;
    const f32x4 e = *reinterpret_cast<const f32x4*>(&sEx[rr * 128 + w4 * 4]);
    dst[idx] = e * (f32x4)sEy[rr * 128 + h];
  }
}

// Sum 32 bf16 kc-partials per image, apply 1/HW; also copy out_params.
__global__ __launch_bounds__(256) void reduce_kernel(
    const short* __restrict__ partials, const float* __restrict__ roi,
    float* __restrict__ outF, float* __restrict__ out_params) {
  const int idx = blockIdx.x * 256 + threadIdx.x;   // f32x4 index, 65536 total
  const int n   = idx >> 12;                        // 4096 f32x4 per image
  const int i4  = idx & 4095;
  const short4v* p =
      reinterpret_cast<const short4v*>(partials) + (size_t)n * 32 * 4096 + i4;
  f32x4 s = (f32x4)0.0f;
#pragma unroll
  for (int kc = 0; kc < 32; ++kc) {
    const short4v v = p[(size_t)kc * 4096];
    s.x += bf2f(v.x); s.y += bf2f(v.y); s.z += bf2f(v.z); s.w += bf2f(v.w);
  }
  s *= (1.0f / (float)HW);
  reinterpret_cast<f32x4*>(outF)[idx] = s;
  if (idx < NB * RB * 4) out_params[idx] = roi[idx];
}

extern "C" void kernel_launch(void* const* d_in, const int* in_sizes, int n_in,
                              void* d_out, int out_size, void* d_ws, size_t ws_size,
                              hipStream_t stream) {
  const float* x   = (const float*)d_in[0];
  const float* roi = (const float*)d_in[1];
  float* out        = (float*)d_out;
  float* out_feat   = out;                         // 16*64*256
  float* out_params = out + NB * RB * DB;          // 16*64*4
  float* out_map    = out_params + NB * RB * 4;    // 16*64*128*128 (67 MB)

  const size_t par_shorts = 512u * RB * DB;        // 8.39M bf16 (16.8 MB)
  const bool ws_ok = ws_size >= par_shorts * sizeof(short) + 64;

  if (ws_ok) {
    // 2 dispatches: feat(512)+map(256 tail) fused, then reduce(+params)
    short* P = (short*)d_ws;
    feat_kernel<true><<<768, 256, 0, stream>>>(x, roi, P, out_map);
    reduce_kernel<<<256, 256, 0, stream>>>(P, roi, out_feat, out_params);
  } else {
    // fallback: partials at out_map head; map written last
    short* P = (short*)out_map;
    feat_kernel<false><<<512, 256, 0, stream>>>(x, roi, P, out_map);
    reduce_kernel<<<256, 256, 0, stream>>>(P, roi, out_feat, out_params);
    map_only_kernel<<<256, 256, 0, stream>>>(roi, out_map);
  }
}

// Round 17
// 94.890 us; speedup vs baseline: 1.0526x; 1.0526x over previous
//
#include <hip/hip_runtime.h>
#include <hip/hip_bf16.h>
#include <math.h>

#define NB 16
#define RB 64
#define HB 128
#define WB 128
#define DB 256
#define HW (HB * WB)

typedef __attribute__((ext_vector_type(8))) short bf16x8;
typedef __attribute__((ext_vector_type(4))) short short4v;
typedef __attribute__((ext_vector_type(4))) float f32x4;

static __device__ __forceinline__ short f2bf(float f) {
  __hip_bfloat16 h = __float2bfloat16(f);
  return *reinterpret_cast<short*>(&h);
}
static __device__ __forceinline__ float bf2f(short s) {
  return __uint_as_float(((unsigned)(unsigned short)s) << 16);
}

// async global->LDS, 16B per lane: HW writes wave-uniform LDS base + lane*16
#define GLOAD_LDS16(gp, lp)                                          \
  __builtin_amdgcn_global_load_lds(                                  \
      (const __attribute__((address_space(1))) unsigned int*)(gp),   \
      (__attribute__((address_space(3))) unsigned int*)(lp), 16, 0, 0)

// Analytic per-axis max of -(|g-mu|/sg)^2 over grid g_i=(i+0.5)/128:
// attained at the grid point nearest mu (R10-verified bitwise vs reduction).
static __device__ __forceinline__ float axis_maxlog(float mu, float sg) {
  int i = (int)roundf(mu * 128.0f - 0.5f);
  i = i < 0 ? 0 : (i > 127 ? 127 : i);
  const float g = (i + 0.5f) * (1.0f / 128.0f);
  const float tm = fabsf(g - mu) / sg;
  return -(tm * tm);
}

// feat v9 (R11 champion, 94.9us): 256 blocks = (n:16 x kc:16), 1024 px
// (8 h-rows) per block, 32 K-steps through the 4x32KB counted-vmcnt
// pipeline. Epilogue: bf16 partial tile + this block's map slice (one
// h-row per wave, analytic recompute) -- plain coalesced stores AFTER the
// last counted wait (R8 lesson: never put extra vmem inside the loop).
template <bool WMAP>
__global__ __launch_bounds__(512, 1) void fused_kernel(
    const float* __restrict__ x, const float* __restrict__ roi,
    short* __restrict__ partials, float* __restrict__ out_map) {
  __shared__ float buf[4][32 * DB];     // 128 KB

  const int bid = blockIdx.x;
  const int n   = bid >> 4;
  const int kc  = bid & 15;
  const int t   = threadIdx.x;
  const int l   = t & 63;
  const int wv  = t >> 6;               // 0..7
  const int mh  = wv >> 2;              // roi half
  const int dw  = wv & 3;               // d-slice
  const int l15 = l & 15;
  const int lk  = (l >> 4) * 8;         // lane's k-offset within a k-step
  const int h0  = kc * 8;               // first h-row of this chunk
  const int dbase = dw * 64 + l15 * 4;

  const char* gx =
      (const char*)(x + ((size_t)n * HW + (size_t)kc * 1024) * DB);
  char* lbase = (char*)&buf[0][0];

  // ---- prologue: analytic tables in registers ----
  f32x4 exr[2][4][2];                   // [rf_local][ks][half]
  float eyv[8][2];                      // [hh][rf_local]
#pragma unroll
  for (int rf = 0; rf < 2; ++rf) {
    const int nr = n * RB + mh * 32 + rf * 16 + l15;
    const float4 rp = reinterpret_cast<const float4*>(roi)[nr];
    const float mlx = axis_maxlog(rp.x, rp.z);
    const float mly = axis_maxlog(rp.y, rp.w);
    const float em  = expf(mlx + mly);
    const float s   = em / (em + 1e-12f);
#pragma unroll
    for (int ks = 0; ks < 4; ++ks) {
#pragma unroll
      for (int hf = 0; hf < 2; ++hf) {
        f32x4 v;
#pragma unroll
        for (int j = 0; j < 4; ++j) {
          const int col = ks * 32 + lk + hf * 4 + j;
          const float g = (col + 0.5f) * (1.0f / 128.0f);
          const float tx = fabsf(g - rp.x) / rp.z;
          v[j] = expf(-(tx * tx) - mlx);
        }
        exr[rf][ks][hf] = v;
      }
    }
#pragma unroll
    for (int hh = 0; hh < 8; ++hh) {
      const float g = (h0 + hh + 0.5f) * (1.0f / 128.0f);
      const float ty = fabsf(g - rp.y) / rp.w;
      eyv[hh][rf] = expf(-(ty * ty) - mly) * s;
    }
  }
  asm volatile("s_waitcnt vmcnt(0)" ::: "memory");  // vmcnt tracks staging only

  f32x4 acc[2][4];
#pragma unroll
  for (int rf = 0; rf < 2; ++rf)
#pragma unroll
    for (int f = 0; f < 4; ++f) acc[rf][f] = (f32x4)0.0f;

  // staging: 512 threads x 16B x 4 passes = 32KB buffer
#define STAGE(bi, slot) do {                                                 \
    const char* gsrc_ = gx + (size_t)(bi) * 32768;                           \
    char* ldst_ = lbase + (slot) * 32768;                                    \
    _Pragma("unroll")                                                        \
    for (int ii = 0; ii < 4; ++ii)                                           \
      GLOAD_LDS16(gsrc_ + ii * 8192 + wv * 1024 + l * 16,                    \
                  ldst_ + ii * 8192 + wv * 1024);                            \
  } while (0)

  STAGE(0, 0); STAGE(1, 1); STAGE(2, 2);   // 12 loads in flight per wave

#define KSTEP(bi, VM, DO_STAGE) do {                                         \
    asm volatile("s_waitcnt vmcnt(" #VM ")" ::: "memory");                   \
    __builtin_amdgcn_s_barrier();                                            \
    __builtin_amdgcn_sched_barrier(0);                                       \
    if (DO_STAGE) STAGE((bi) + 3, ((bi) + 3) & 3);                           \
    const float* bp_ = &buf[(bi) & 3][0];                                    \
    f32x4 xv_[8];                                                            \
    _Pragma("unroll")                                                        \
    for (int j = 0; j < 8; ++j)                                              \
      xv_[j] = *reinterpret_cast<const f32x4*>(                              \
          bp_ + (lk + j) * DB + dbase);                                      \
    bf16x8 bfr_[4];                                                          \
    _Pragma("unroll")                                                        \
    for (int f = 0; f < 4; ++f) {                                            \
      bf16x8 b_;                                                             \
      _Pragma("unroll")                                                      \
      for (int j = 0; j < 8; ++j) b_[j] = f2bf(xv_[j][f]);                   \
      bfr_[f] = b_;                                                          \
    }                                                                        \
    bf16x8 afr_[2];                                                          \
    _Pragma("unroll")                                                        \
    for (int rf = 0; rf < 2; ++rf) {                                         \
      const float ey_ = eyv[(bi) >> 2][rf];                                  \
      const f32x4 e0_ = exr[rf][(bi) & 3][0];                                \
      const f32x4 e1_ = exr[rf][(bi) & 3][1];                                \
      bf16x8 a_;                                                             \
      a_[0] = f2bf(ey_ * e0_.x); a_[1] = f2bf(ey_ * e0_.y);                  \
      a_[2] = f2bf(ey_ * e0_.z); a_[3] = f2bf(ey_ * e0_.w);                  \
      a_[4] = f2bf(ey_ * e1_.x); a_[5] = f2bf(ey_ * e1_.y);                  \
      a_[6] = f2bf(ey_ * e1_.z); a_[7] = f2bf(ey_ * e1_.w);                  \
      afr_[rf] = a_;                                                         \
    }                                                                        \
    _Pragma("unroll")                                                        \
    for (int rf = 0; rf < 2; ++rf)                                           \
      _Pragma("unroll")                                                      \
      for (int f = 0; f < 4; ++f)                                            \
        acc[rf][f] = __builtin_amdgcn_mfma_f32_16x16x32_bf16(                \
            afr_[rf], bfr_[f], acc[rf][f], 0, 0, 0);                         \
  } while (0)

  KSTEP(0, 8, 1);   KSTEP(1, 8, 1);   KSTEP(2, 8, 1);   KSTEP(3, 8, 1);
  KSTEP(4, 8, 1);   KSTEP(5, 8, 1);   KSTEP(6, 8, 1);   KSTEP(7, 8, 1);
  KSTEP(8, 8, 1);   KSTEP(9, 8, 1);   KSTEP(10, 8, 1);  KSTEP(11, 8, 1);
  KSTEP(12, 8, 1);  KSTEP(13, 8, 1);  KSTEP(14, 8, 1);  KSTEP(15, 8, 1);
  KSTEP(16, 8, 1);  KSTEP(17, 8, 1);  KSTEP(18, 8, 1);  KSTEP(19, 8, 1);
  KSTEP(20, 8, 1);  KSTEP(21, 8, 1);  KSTEP(22, 8, 1);  KSTEP(23, 8, 1);
  KSTEP(24, 8, 1);  KSTEP(25, 8, 1);  KSTEP(26, 8, 1);  KSTEP(27, 8, 1);
  KSTEP(28, 8, 1);  KSTEP(29, 8, 0);  KSTEP(30, 4, 0);  KSTEP(31, 0, 0);

#undef KSTEP
#undef STAGE

  // ---- epilogue 1: bf16 partial tile, plain coalesced 8B stores ----
  // D layout: col = lane&15 (-> d, +f over vector), row = (lane>>4)*4 + reg.
  short* P = partials + (size_t)bid * (RB * DB);
#pragma unroll
  for (int rf = 0; rf < 2; ++rf) {
#pragma unroll
    for (int reg = 0; reg < 4; ++reg) {
      const int r = mh * 32 + rf * 16 + (l >> 4) * 4 + reg;
      short4v v;
      v.x = f2bf(acc[rf][0][reg]); v.y = f2bf(acc[rf][1][reg]);
      v.z = f2bf(acc[rf][2][reg]); v.w = f2bf(acc[rf][3][reg]);
      *reinterpret_cast<short4v*>(P + (size_t)r * DB + dbase) = v;
    }
  }

  // ---- epilogue 2: this block's map slice. Wave wv owns h-row h0+wv,
  // all 64 rois x 128 w; values recomputed analytically (L1-hot roi). ----
  if constexpr (WMAP) {
    const int h  = h0 + wv;
    const int p4 = l & 31;              // w-quad
    const float gh = (h + 0.5f) * (1.0f / 128.0f);
#pragma unroll 4
    for (int it = 0; it < 32; ++it) {
      const int r = it * 2 + (l >> 5);
      const float4 rp = reinterpret_cast<const float4*>(roi)[n * RB + r];
      const float mlx = axis_maxlog(rp.x, rp.z);
      const float mly = axis_maxlog(rp.y, rp.w);
      const float em  = expf(mlx + mly);
      const float s   = em / (em + 1e-12f);
      const float ty  = fabsf(gh - rp.y) / rp.w;
      const float ey  = expf(-(ty * ty) - mly) * s;
      f32x4 v;
#pragma unroll
      for (int j = 0; j < 4; ++j) {
        const float g  = (p4 * 4 + j + 0.5f) * (1.0f / 128.0f);
        const float tx = fabsf(g - rp.x) / rp.z;
        v[j] = expf(-(tx * tx) - mlx) * ey;
      }
      *reinterpret_cast<f32x4*>(
          out_map + ((size_t)(n * RB + r) * HB + h) * WB + p4 * 4) = v;
    }
  }
}

// Standalone analytic map writer (fallback path only).
__global__ __launch_bounds__(512) void map_only_kernel(
    const float* __restrict__ roi, float* __restrict__ out_map) {
  __shared__ float sT[1024];
  const int mb = blockIdx.x;            // 0..255, 4 rois each
  const int t  = threadIdx.x;
  float* sEx = sT;
  float* sEy = sT + 512;
  for (int v = t; v < 1024; v += 512) {
    const int rr = v >> 8, axis = (v >> 7) & 1, pos = v & 127;
    const float4 rp = reinterpret_cast<const float4*>(roi)[mb * 4 + rr];
    const float mlx = axis_maxlog(rp.x, rp.z);
    const float mly = axis_maxlog(rp.y, rp.w);
    const float em  = expf(mlx + mly);
    const float s   = em / (em + 1e-12f);
    const float g   = (pos + 0.5f) * (1.0f / 128.0f);
    if (axis == 0) {
      const float tx = fabsf(g - rp.x) / rp.z;
      sEx[rr * 128 + pos] = expf(-(tx * tx) - mlx);
    } else {
      const float ty = fabsf(g - rp.y) / rp.w;
      sEy[rr * 128 + pos] = expf(-(ty * ty) - mly) * s;
    }
  }
  __syncthreads();
  f32x4* dst = reinterpret_cast<f32x4*>(out_map + (size_t)mb * 4 * HW);
#pragma unroll
  for (int p = 0; p < 32; ++p) {
    const int idx = p * 512 + t;
    const int rr = idx >> 12, h = (idx >> 5) & 127, w4 = idx & 31;
    const f32x4 e = *reinterpret_cast<const f32x4*>(&sEx[rr * 128 + w4 * 4]);
    dst[idx] = e * (f32x4)sEy[rr * 128 + h];
  }
}

// Sum 16 bf16 kc-partials per image, apply 1/HW; also copy out_params.
__global__ __launch_bounds__(256) void reduce_kernel(
    const short* __restrict__ partials, const float* __restrict__ roi,
    float* __restrict__ outF, float* __restrict__ out_params) {
  const int idx = blockIdx.x * 256 + threadIdx.x;   // f32x4 index, 65536 total
  const int n   = idx >> 12;                        // 4096 f32x4 per image
  const int i4  = idx & 4095;
  const short4v* p =
      reinterpret_cast<const short4v*>(partials) + (size_t)n * 16 * 4096 + i4;
  f32x4 s = (f32x4)0.0f;
#pragma unroll
  for (int kc = 0; kc < 16; ++kc) {
    const short4v v = p[(size_t)kc * 4096];
    s.x += bf2f(v.x); s.y += bf2f(v.y); s.z += bf2f(v.z); s.w += bf2f(v.w);
  }
  s *= (1.0f / (float)HW);
  reinterpret_cast<f32x4*>(outF)[idx] = s;
  if (idx < NB * RB * 4) out_params[idx] = roi[idx];
}

extern "C" void kernel_launch(void* const* d_in, const int* in_sizes, int n_in,
                              void* d_out, int out_size, void* d_ws, size_t ws_size,
                              hipStream_t stream) {
  const float* x   = (const float*)d_in[0];
  const float* roi = (const float*)d_in[1];
  float* out        = (float*)d_out;
  float* out_feat   = out;                         // 16*64*256
  float* out_params = out + NB * RB * DB;          // 16*64*4
  float* out_map    = out_params + NB * RB * 4;    // 16*64*128*128 (67 MB)

  const size_t par_shorts = 256u * RB * DB;        // 4.19M bf16 (8.4 MB)
  const bool ws_ok = ws_size >= par_shorts * sizeof(short) + 64;

  if (ws_ok) {
    // 2 dispatches: fused feat+map, then reduce(+params)
    short* P = (short*)d_ws;
    fused_kernel<true><<<256, 512, 0, stream>>>(x, roi, P, out_map);
    reduce_kernel<<<256, 256, 0, stream>>>(P, roi, out_feat, out_params);
  } else {
    // fallback: bf16 partials at out_map head; map written last
    short* P = (short*)out_map;
    fused_kernel<false><<<256, 512, 0, stream>>>(x, roi, P, out_map);
    reduce_kernel<<<256, 256, 0, stream>>>(P, roi, out_feat, out_params);
    map_only_kernel<<<256, 512, 0, stream>>>(roi, out_map);
  }
}